// Round 3
// baseline (515.422 us; speedup 1.0000x reference)
//
#include <hip/hip_runtime.h>
#include <cstdint>
#include <cstddef>

#define NTOK 8192
#define DMODEL 768
#define NEXP 16
#define HDIM 3072
#define CAP 640
#define BLDP 72   // padded LDS row stride (elements) for transposed B tiles

typedef __attribute__((ext_vector_type(8))) short short8v;
typedef __attribute__((ext_vector_type(4))) float f32x4;

static __device__ __forceinline__ unsigned short f2bf(float f){
  union { float f; unsigned int u; } v; v.f = f;
  unsigned int u = v.u;
  unsigned int r = (u + 0x7FFFu + ((u >> 16) & 1u)) >> 16;
  return (unsigned short)r;
}

// async global(16B per lane) -> LDS (wave-uniform base + lane*16)
static __device__ __forceinline__ void gload16(const unsigned short* g, unsigned short* l){
  __builtin_amdgcn_global_load_lds(
      (const __attribute__((address_space(1))) unsigned int*)g,
      (__attribute__((address_space(3))) unsigned int*)l, 16, 0, 0);
}

// Stage a 64k x (NCOLQ*4)n f32 tile, converting to bf16 and transposing into
// LDS [n][BLDP] (k-contiguous rows). 4x4 in-register micro-transpose.
// Reads: float4 coalesced along n. Writes: ds_write_b64, ~4-way banks (1.58x).
template<int NCOLQ>
static __device__ __forceinline__ void stageB(
    const float* __restrict__ gsrc, int ldg, unsigned short* __restrict__ lds, int tid)
{
  const int nq  = tid % NCOLQ;
  const int kq0 = tid / NCOLQ;
  const int KQSTEP = 256 / NCOLQ;
  #pragma unroll
  for (int i = 0; i < (16 * NCOLQ) / 256; i++){
    int kq = kq0 + i * KQSTEP;
    const float* s = gsrc + (size_t)(kq * 4) * ldg + nq * 4;
    float4 r0 = *(const float4*)(s);
    float4 r1 = *(const float4*)(s + ldg);
    float4 r2 = *(const float4*)(s + 2 * ldg);
    float4 r3 = *(const float4*)(s + 3 * ldg);
    ushort4 c0 = { f2bf(r0.x), f2bf(r1.x), f2bf(r2.x), f2bf(r3.x) };
    ushort4 c1 = { f2bf(r0.y), f2bf(r1.y), f2bf(r2.y), f2bf(r3.y) };
    ushort4 c2 = { f2bf(r0.z), f2bf(r1.z), f2bf(r2.z), f2bf(r3.z) };
    ushort4 c3 = { f2bf(r0.w), f2bf(r1.w), f2bf(r2.w), f2bf(r3.w) };
    unsigned short* d = lds + (nq * 4) * BLDP + kq * 4;
    *(ushort4*)(d)             = c0;
    *(ushort4*)(d + BLDP)      = c1;
    *(ushort4*)(d + 2 * BLDP)  = c2;
    *(ushort4*)(d + 3 * BLDP)  = c3;
  }
}

// ---------------- init expert_tok = -1 ----------------
__global__ void init_tok_kernel(int* __restrict__ expert_tok){
  int i = blockIdx.x * 256 + threadIdx.x;   // 40*256 = 10240 exact
  expert_tok[i] = -1;
}

// ---------------- router: logits, softmax-gate, argmax ----------------
__global__ __launch_bounds__(256) void router_kernel(
    const float* __restrict__ x, const float* __restrict__ Wr,
    int* __restrict__ eid, float* __restrict__ gate)
{
  int t = blockIdx.x * 4 + (threadIdx.x >> 6);
  int lane = threadIdx.x & 63;
  const float* xr = x + (size_t)t * DMODEL;
  float acc[16];
  #pragma unroll
  for (int e = 0; e < 16; e++) acc[e] = 0.f;
  #pragma unroll
  for (int i = 0; i < 12; i++){
    float xv = xr[lane + i * 64];
    const float* wrow = Wr + (size_t)(lane + i * 64) * 16;
    #pragma unroll
    for (int e = 0; e < 16; e++) acc[e] += xv * wrow[e];
  }
  #pragma unroll
  for (int e = 0; e < 16; e++){
    float v = acc[e];
    #pragma unroll
    for (int off = 32; off >= 1; off >>= 1) v += __shfl_xor(v, off, 64);
    acc[e] = v;
  }
  if (lane == 0){
    float mx = acc[0]; int bi = 0;
    #pragma unroll
    for (int e = 1; e < 16; e++) if (acc[e] > mx){ mx = acc[e]; bi = e; }
    float s = 0.f;
    #pragma unroll
    for (int e = 0; e < 16; e++) s += __expf(acc[e] - mx);
    eid[t] = bi;
    gate[t] = 1.0f / s;   // softmax value at the argmax
  }
}

// ---------------- order-preserving slot scan (1 block) ----------------
__global__ __launch_bounds__(256) void scan_route_kernel(
    const int* __restrict__ eid, const float* __restrict__ gate,
    int* __restrict__ expert_tok, float* __restrict__ cw, int* __restrict__ dropped)
{
  __shared__ int hist[256][16];
  int t = threadIdx.x;
  #pragma unroll
  for (int e = 0; e < 16; e++) hist[t][e] = 0;
  __syncthreads();
  for (int i = 0; i < 32; i++){
    int tok = t * 32 + i;
    hist[t][eid[tok]]++;
  }
  __syncthreads();
  if (t < 16){
    int run = 0;
    for (int i = 0; i < 256; i++){ int c = hist[i][t]; hist[i][t] = run; run += c; }
  }
  __syncthreads();
  for (int i = 0; i < 32; i++){
    int tok = t * 32 + i;
    int e = eid[tok];
    int slot = hist[t][e]++;
    if (slot < CAP){
      expert_tok[e * CAP + slot] = tok;
      cw[e * CAP + slot] = gate[tok];
      dropped[tok] = 0;
    } else {
      dropped[tok] = 1;
    }
  }
}

// ---------------- gather x rows -> bf16 [E][C][D] ----------------
__global__ __launch_bounds__(192) void gather_x_kernel(
    const float* __restrict__ x, const int* __restrict__ expert_tok,
    unsigned short* __restrict__ xa)
{
  int ec = blockIdx.x;
  int token = expert_tok[ec];
  int t4 = threadIdx.x * 4;
  ushort4 o;
  if (token >= 0){
    const float4 v = *(const float4*)(x + (size_t)token * DMODEL + t4);
    o.x = f2bf(v.x); o.y = f2bf(v.y); o.z = f2bf(v.z); o.w = f2bf(v.w);
  } else {
    o.x = 0; o.y = 0; o.z = 0; o.w = 0;
  }
  *(ushort4*)(xa + (size_t)ec * DMODEL + t4) = o;
}

// ---------------- GEMM1: xa @ W1 (natural layout, fused cvt) + swiglu -> act bf16 ----
// A: bf16 [E][640][768] via gload16, linear LDS [128][64].
// B: f32 W1 [E][768][6144] staged transposed+converted into LDS [128][BLDP].
__global__ __launch_bounds__(256, 2) void gemm1_swiglu_kernel(
    const unsigned short* __restrict__ xa,
    const float* __restrict__ W1,
    const float* __restrict__ b1,
    unsigned short* __restrict__ act)
{
  __shared__ unsigned short As [128 * 64];
  __shared__ unsigned short Bgs[128 * BLDP];
  __shared__ unsigned short Bus[128 * BLDP];
  // bijective XCD-chunk swizzle: 1920 blocks, 240 per XCD; m fastest within chunk
  const int b = blockIdx.x;
  const int w = (b & 7) * 240 + (b >> 3);
  const int mb = w % 5;
  const int nb = (w / 5) % 24;
  const int e  = w / 120;
  const int m0 = mb * 128;
  const int n0 = nb * 128;
  const int tid  = threadIdx.x;
  const int lane = tid & 63;
  const int wv   = tid >> 6;
  const int wr   = (wv >> 1) * 64;
  const int wc   = (wv & 1) * 64;
  const int fr   = lane & 15;
  const int kg   = lane >> 4;

  const unsigned short* Ag = xa + ((size_t)e * 640 + m0) * 768;
  const float* Bg = W1 + (size_t)e * 768 * 6144 + n0;
  const float* Bu = W1 + (size_t)e * 768 * 6144 + 3072 + n0;

  const int srow = wv * 8 + (lane >> 3);
  const int scol = (lane & 7) * 8;
  unsigned short* ldsA = As + wv * 512;

  f32x4 accg[4][4], accu[4][4];
  f32x4 zero4 = {0.f, 0.f, 0.f, 0.f};
  #pragma unroll
  for (int m = 0; m < 4; m++)
    #pragma unroll
    for (int n = 0; n < 4; n++){ accg[m][n] = zero4; accu[m][n] = zero4; }

  for (int kt = 0; kt < 768; kt += 64){
    #pragma unroll
    for (int c = 0; c < 4; c++){
      int r = c * 32 + srow;
      gload16(Ag + (size_t)r * 768 + kt + scol, ldsA + c * 2048);
    }
    stageB<32>(Bg + (size_t)kt * 6144, 6144, Bgs, tid);
    stageB<32>(Bu + (size_t)kt * 6144, 6144, Bus, tid);
    __syncthreads();
    #pragma unroll
    for (int kk = 0; kk < 2; kk++){
      short8v af[4], bg[4], bu[4];
      #pragma unroll
      for (int m = 0; m < 4; m++)
        af[m] = *(const short8v*)(As + (wr + m * 16 + fr) * 64 + kk * 32 + kg * 8);
      #pragma unroll
      for (int n = 0; n < 4; n++){
        bg[n] = *(const short8v*)(Bgs + (wc + n * 16 + fr) * BLDP + kk * 32 + kg * 8);
        bu[n] = *(const short8v*)(Bus + (wc + n * 16 + fr) * BLDP + kk * 32 + kg * 8);
      }
      #pragma unroll
      for (int m = 0; m < 4; m++)
        #pragma unroll
        for (int n = 0; n < 4; n++){
          accg[m][n] = __builtin_amdgcn_mfma_f32_16x16x32_bf16(af[m], bg[n], accg[m][n], 0, 0, 0);
          accu[m][n] = __builtin_amdgcn_mfma_f32_16x16x32_bf16(af[m], bu[n], accu[m][n], 0, 0, 0);
        }
    }
    __syncthreads();
  }
  // epilogue: h_gate/h_up (+bias) -> silu(g)*u -> bf16 act
  #pragma unroll
  for (int n = 0; n < 4; n++){
    int col = n0 + wc + n * 16 + fr;
    float b_g = b1[(size_t)e * 6144 + col];
    float b_u = b1[(size_t)e * 6144 + 3072 + col];
    #pragma unroll
    for (int m = 0; m < 4; m++){
      #pragma unroll
      for (int r = 0; r < 4; r++){
        int row = m0 + wr + m * 16 + kg * 4 + r;
        float hg = accg[m][n][r] + b_g;
        float hu = accu[m][n][r] + b_u;
        float s = (hg / (1.0f + __expf(-hg))) * hu;
        act[((size_t)e * 640 + row) * 3072 + col] = f2bf(s);
      }
    }
  }
}

// ---------------- GEMM2: act @ W2 (natural layout, fused cvt) + b2 -> y f32 ----------
// BM=128 x BN=64, 960 blocks. A: act bf16 gload16. B: f32 W2 [E][3072][768] staged.
__global__ __launch_bounds__(256, 3) void gemm2_kernel(
    const unsigned short* __restrict__ act,
    const float* __restrict__ W2,
    const float* __restrict__ b2,
    float* __restrict__ y)                   // [E][640][768]
{
  __shared__ unsigned short As[128 * 64];
  __shared__ unsigned short Bs[64 * BLDP];
  const int b = blockIdx.x;
  const int w = (b & 7) * 120 + (b >> 3);
  const int mb = w % 5;
  const int nb = (w / 5) % 12;
  const int e  = w / 60;
  const int m0 = mb * 128;
  const int n0 = nb * 64;
  const int tid  = threadIdx.x;
  const int lane = tid & 63;
  const int wv   = tid >> 6;
  const int wr   = (wv & 1) * 64;
  const int wc   = (wv >> 1) * 32;
  const int fr   = lane & 15;
  const int kg   = lane >> 4;

  const unsigned short* Ag = act + ((size_t)e * 640 + m0) * 3072;
  const float* Bg = W2 + (size_t)e * 3072 * 768 + n0;

  const int srow = wv * 8 + (lane >> 3);
  const int scol = (lane & 7) * 8;
  unsigned short* ldsA = As + wv * 512;

  f32x4 acc[4][2];
  f32x4 zero4 = {0.f, 0.f, 0.f, 0.f};
  #pragma unroll
  for (int m = 0; m < 4; m++)
    #pragma unroll
    for (int n = 0; n < 2; n++) acc[m][n] = zero4;

  for (int kt = 0; kt < 3072; kt += 64){
    #pragma unroll
    for (int c = 0; c < 4; c++){
      int r = c * 32 + srow;
      gload16(Ag + (size_t)r * 3072 + kt + scol, ldsA + c * 2048);
    }
    stageB<16>(Bg + (size_t)kt * 768, 768, Bs, tid);
    __syncthreads();
    #pragma unroll
    for (int kk = 0; kk < 2; kk++){
      short8v af[4], bf[2];
      #pragma unroll
      for (int m = 0; m < 4; m++)
        af[m] = *(const short8v*)(As + (wr + m * 16 + fr) * 64 + kk * 32 + kg * 8);
      #pragma unroll
      for (int n = 0; n < 2; n++)
        bf[n] = *(const short8v*)(Bs + (wc + n * 16 + fr) * BLDP + kk * 32 + kg * 8);
      #pragma unroll
      for (int m = 0; m < 4; m++)
        #pragma unroll
        for (int n = 0; n < 2; n++)
          acc[m][n] = __builtin_amdgcn_mfma_f32_16x16x32_bf16(af[m], bf[n], acc[m][n], 0, 0, 0);
    }
    __syncthreads();
  }
  float b2v[2];
  #pragma unroll
  for (int n = 0; n < 2; n++) b2v[n] = b2[(size_t)e * 768 + n0 + wc + n * 16 + fr];
  #pragma unroll
  for (int m = 0; m < 4; m++){
    #pragma unroll
    for (int r = 0; r < 4; r++){
      int row = m0 + wr + m * 16 + kg * 4 + r;
      #pragma unroll
      for (int n = 0; n < 2; n++){
        int col = n0 + wc + n * 16 + fr;
        y[((size_t)e * 640 + row) * 768 + col] = acc[m][n][r] + b2v[n];
      }
    }
  }
}

// ---------------- combine-weight scatter: y[e][c] * cw -> out[token] ----------------
__global__ __launch_bounds__(192) void combine_scatter_kernel(
    const float* __restrict__ y, const int* __restrict__ expert_tok,
    const float* __restrict__ cw, float* __restrict__ out)
{
  int ec = blockIdx.x;
  int token = expert_tok[ec];
  if (token < 0) return;
  float w = cw[ec];
  int t4 = threadIdx.x * 4;
  float4 v = *(const float4*)(y + (size_t)ec * 768 + t4);
  v.x *= w; v.y *= w; v.z *= w; v.w *= w;
  *(float4*)(out + (size_t)token * 768 + t4) = v;
}

// ---------------- dense fallback for dropped tokens only ----------------
__global__ __launch_bounds__(256) void fallback_kernel(
    const float* __restrict__ x,
    const float* __restrict__ W1f, const float* __restrict__ b1f,
    const float* __restrict__ W2f, const float* __restrict__ b2f,
    const int* __restrict__ dropped, float* __restrict__ out)
{
  int t = blockIdx.x;
  if (dropped[t] == 0) return;
  __shared__ float xs[768];
  __shared__ float hs[6144];
  int tid = threadIdx.x;
  for (int d = tid; d < 768; d += 256) xs[d] = x[(size_t)t * 768 + d];
  __syncthreads();
  for (int j = tid; j < 6144; j += 256){
    float a = b1f[j];
    for (int d = 0; d < 768; d++) a += xs[d] * W1f[(size_t)d * 6144 + j];
    hs[j] = a;
  }
  __syncthreads();
  for (int j = tid; j < 3072; j += 256){
    float hg = hs[j], hu = hs[j + 3072];
    hs[j] = (hg / (1.0f + __expf(-hg))) * hu;
  }
  __syncthreads();
  for (int d = tid; d < 768; d += 256){
    float a = b2f[d];
    for (int h = 0; h < 3072; h++) a += hs[h] * W2f[(size_t)h * 768 + d];
    out[(size_t)t * 768 + d] = a;   // FALLBACK_W = 1.0
  }
}

extern "C" void kernel_launch(void* const* d_in, const int* in_sizes, int n_in,
                              void* d_out, int out_size, void* d_ws, size_t ws_size,
                              hipStream_t stream) {
  const float* x   = (const float*)d_in[0];
  const float* Wr  = (const float*)d_in[1];
  const float* W1  = (const float*)d_in[2];
  const float* b1  = (const float*)d_in[3];
  const float* W2  = (const float*)d_in[4];
  const float* b2  = (const float*)d_in[5];
  const float* W1f = (const float*)d_in[6];
  const float* b1f = (const float*)d_in[7];
  const float* W2f = (const float*)d_in[8];
  const float* b2f = (const float*)d_in[9];
  float* out = (float*)d_out;

  char* ws = (char*)d_ws;
  int*            expert_tok = (int*)  (ws + 0);          // 16*640*4 = 40960
  float*          cw         = (float*)(ws + 40960);
  int*            eid        = (int*)  (ws + 81920);
  float*          gate       = (float*)(ws + 114688);
  int*            drop       = (int*)  (ws + 147456);
  unsigned short* xa         = (unsigned short*)(ws + 180224);     // 16*640*768*2  = 15728640
  unsigned short* act        = (unsigned short*)(ws + 15908864);   // 16*640*3072*2 = 62914560
  float*          y          = (float*)(ws + 78823424);            // 16*640*768*4  = 31457280
  // total ws use: ~110 MB

  init_tok_kernel<<<40, 256, 0, stream>>>(expert_tok);
  router_kernel<<<2048, 256, 0, stream>>>(x, Wr, eid, gate);
  scan_route_kernel<<<1, 256, 0, stream>>>(eid, gate, expert_tok, cw, drop);
  gather_x_kernel<<<16 * CAP, 192, 0, stream>>>(x, expert_tok, xa);
  gemm1_swiglu_kernel<<<1920, 256, 0, stream>>>(xa, W1, b1, act);
  gemm2_kernel<<<960, 256, 0, stream>>>(act, W2, b2, y);
  combine_scatter_kernel<<<16 * CAP, 192, 0, stream>>>(y, expert_tok, cw, out);
  fallback_kernel<<<NTOK, 256, 0, stream>>>(x, W1f, b1f, W2f, b2f, drop, out);
}

// Round 4
// 384.860 us; speedup vs baseline: 1.3392x; 1.3392x over previous
//
#include <hip/hip_runtime.h>
#include <cstdint>
#include <cstddef>

#define NTOK 8192
#define DMODEL 768
#define NEXP 16
#define HDIM 3072
#define CAP 640
#define BLDP 72   // LDS row stride (elems) for B tiles; 144B, 16B-aligned rows

typedef __attribute__((ext_vector_type(8))) short short8v;
typedef __attribute__((ext_vector_type(4))) float f32x4;

static __device__ __forceinline__ unsigned short f2bf(float f){
  union { float f; unsigned int u; } v; v.f = f;
  unsigned int u = v.u;
  unsigned int r = (u + 0x7FFFu + ((u >> 16) & 1u)) >> 16;
  return (unsigned short)r;
}

// async global(16B per lane) -> LDS (wave-uniform base + lane*16)
static __device__ __forceinline__ void gload16(const unsigned short* g, unsigned short* l){
  __builtin_amdgcn_global_load_lds(
      (const __attribute__((address_space(1))) unsigned int*)g,
      (__attribute__((address_space(3))) unsigned int*)l, 16, 0, 0);
}

// ---- B staging, split load/write for cross-iteration prefetch (T14) ----
// load: f32 [64k][NCOLQ*4 n] tile -> bf16-packed regs (4x4 micro-transpose)
template<int NCOLQ>
static __device__ __forceinline__ void stageB_load_cvt(
    const float* __restrict__ g, int ldg, ushort4* pc, int tid)
{
  const int nq = tid % NCOLQ, kq0 = tid / NCOLQ, STEP = 256 / NCOLQ;
  #pragma unroll
  for (int i = 0; i < (16 * NCOLQ) / 256; i++){
    const float* s = g + (size_t)((kq0 + i * STEP) * 4) * ldg + nq * 4;
    float4 r0 = *(const float4*)(s);
    float4 r1 = *(const float4*)(s + ldg);
    float4 r2 = *(const float4*)(s + 2 * ldg);
    float4 r3 = *(const float4*)(s + 3 * ldg);
    ushort4 c0, c1, c2, c3;
    c0.x = f2bf(r0.x); c0.y = f2bf(r1.x); c0.z = f2bf(r2.x); c0.w = f2bf(r3.x);
    c1.x = f2bf(r0.y); c1.y = f2bf(r1.y); c1.z = f2bf(r2.y); c1.w = f2bf(r3.y);
    c2.x = f2bf(r0.z); c2.y = f2bf(r1.z); c2.z = f2bf(r2.z); c2.w = f2bf(r3.z);
    c3.x = f2bf(r0.w); c3.y = f2bf(r1.w); c3.z = f2bf(r2.w); c3.w = f2bf(r3.w);
    pc[4*i+0] = c0; pc[4*i+1] = c1; pc[4*i+2] = c2; pc[4*i+3] = c3;
  }
}
// write: regs -> LDS [n][BLDP], k-slot XOR-swizzled (write banks at b64 floor)
template<int NCOLQ>
static __device__ __forceinline__ void stageB_write(
    const ushort4* pc, unsigned short* __restrict__ lds, int tid)
{
  const int nq = tid % NCOLQ, kq0 = tid / NCOLQ, STEP = 256 / NCOLQ;
  const int sx = 2 * ((nq >> 1) & 3);
  #pragma unroll
  for (int i = 0; i < (16 * NCOLQ) / 256; i++){
    int q = (kq0 + i * STEP) ^ sx;     // swizzled 4-elem slot
    unsigned short* d = lds + (nq * 4) * BLDP + q * 4;
    *(ushort4*)(d)            = pc[4*i+0];
    *(ushort4*)(d + BLDP)     = pc[4*i+1];
    *(ushort4*)(d + 2 * BLDP) = pc[4*i+2];
    *(ushort4*)(d + 3 * BLDP) = pc[4*i+3];
  }
}

// ---------------- init expert_tok = -1 ----------------
__global__ void init_tok_kernel(int* __restrict__ expert_tok){
  int i = blockIdx.x * 256 + threadIdx.x;   // 40*256 = 10240 exact
  expert_tok[i] = -1;
}

// ---------------- router: logits, softmax-gate, argmax ----------------
__global__ __launch_bounds__(256) void router_kernel(
    const float* __restrict__ x, const float* __restrict__ Wr,
    int* __restrict__ eid, float* __restrict__ gate)
{
  int t = blockIdx.x * 4 + (threadIdx.x >> 6);
  int lane = threadIdx.x & 63;
  const float* xr = x + (size_t)t * DMODEL;
  float acc[16];
  #pragma unroll
  for (int e = 0; e < 16; e++) acc[e] = 0.f;
  #pragma unroll
  for (int i = 0; i < 12; i++){
    float xv = xr[lane + i * 64];
    const float* wrow = Wr + (size_t)(lane + i * 64) * 16;
    #pragma unroll
    for (int e = 0; e < 16; e++) acc[e] += xv * wrow[e];
  }
  #pragma unroll
  for (int e = 0; e < 16; e++){
    float v = acc[e];
    #pragma unroll
    for (int off = 32; off >= 1; off >>= 1) v += __shfl_xor(v, off, 64);
    acc[e] = v;
  }
  if (lane == 0){
    float mx = acc[0]; int bi = 0;
    #pragma unroll
    for (int e = 1; e < 16; e++) if (acc[e] > mx){ mx = acc[e]; bi = e; }
    float s = 0.f;
    #pragma unroll
    for (int e = 0; e < 16; e++) s += __expf(acc[e] - mx);
    eid[t] = bi;
    gate[t] = 1.0f / s;   // softmax value at the argmax
  }
}

// ---------------- order-preserving slot scan (1 block) ----------------
__global__ __launch_bounds__(256) void scan_route_kernel(
    const int* __restrict__ eid, const float* __restrict__ gate,
    int* __restrict__ expert_tok, float* __restrict__ cw, int* __restrict__ dropped)
{
  __shared__ int hist[256][16];
  int t = threadIdx.x;
  #pragma unroll
  for (int e = 0; e < 16; e++) hist[t][e] = 0;
  __syncthreads();
  for (int i = 0; i < 32; i++){
    int tok = t * 32 + i;
    hist[t][eid[tok]]++;
  }
  __syncthreads();
  if (t < 16){
    int run = 0;
    for (int i = 0; i < 256; i++){ int c = hist[i][t]; hist[i][t] = run; run += c; }
  }
  __syncthreads();
  for (int i = 0; i < 32; i++){
    int tok = t * 32 + i;
    int e = eid[tok];
    int slot = hist[t][e]++;
    if (slot < CAP){
      expert_tok[e * CAP + slot] = tok;
      cw[e * CAP + slot] = gate[tok];
      dropped[tok] = 0;
    } else {
      dropped[tok] = 1;
    }
  }
}

// ---------------- gather x rows -> bf16 [E][C][D] ----------------
__global__ __launch_bounds__(192) void gather_x_kernel(
    const float* __restrict__ x, const int* __restrict__ expert_tok,
    unsigned short* __restrict__ xa)
{
  int ec = blockIdx.x;
  int token = expert_tok[ec];
  int t4 = threadIdx.x * 4;
  ushort4 o;
  if (token >= 0){
    const float4 v = *(const float4*)(x + (size_t)token * DMODEL + t4);
    o.x = f2bf(v.x); o.y = f2bf(v.y); o.z = f2bf(v.z); o.w = f2bf(v.w);
  } else {
    o.x = 0; o.y = 0; o.z = 0; o.w = 0;
  }
  *(ushort4*)(xa + (size_t)ec * DMODEL + t4) = o;
}

// ---------------- GEMM1: xa @ W1 (fused cvt) + swiglu -> act bf16 ----------------
__global__ __launch_bounds__(256, 2) void gemm1_swiglu_kernel(
    const unsigned short* __restrict__ xa,
    const float* __restrict__ W1,
    const float* __restrict__ b1,
    unsigned short* __restrict__ act)
{
  __shared__ unsigned short As [128 * 64];
  __shared__ unsigned short Bgs[128 * BLDP];
  __shared__ unsigned short Bus[128 * BLDP];
  // bijective XCD-chunk swizzle: 1920 blocks, 240 per XCD; m fastest within chunk
  const int b = blockIdx.x;
  const int w = (b & 7) * 240 + (b >> 3);
  const int mb = w % 5;
  const int nb = (w / 5) % 24;
  const int e  = w / 120;
  const int m0 = mb * 128;
  const int n0 = nb * 128;
  const int tid  = threadIdx.x;
  const int lane = tid & 63;
  const int wv   = tid >> 6;
  const int wr   = (wv >> 1) * 64;
  const int wc   = (wv & 1) * 64;
  const int fr   = lane & 15;
  const int kg   = lane >> 4;
  const int cA   = fr & 7;       // A-read chunk XOR
  const int f3   = fr >> 3;      // B-read chunk XOR component

  const unsigned short* Ag = xa + ((size_t)e * 640 + m0) * 768;
  const float* Bg = W1 + (size_t)e * 768 * 6144 + n0;
  const float* Bu = W1 + (size_t)e * 768 * 6144 + 3072 + n0;

  // A staging: linear LDS dest; global source chunk-XOR pre-swizzled (G21)
  const int srow = wv * 8 + (lane >> 3);
  const int scol = (((lane & 7) ^ ((lane >> 3) & 7)) * 8);
  unsigned short* ldsA = As + wv * 512;

  f32x4 accg[4][4], accu[4][4];
  f32x4 zero4 = {0.f, 0.f, 0.f, 0.f};
  #pragma unroll
  for (int m = 0; m < 4; m++)
    #pragma unroll
    for (int n = 0; n < 4; n++){ accg[m][n] = zero4; accu[m][n] = zero4; }

  ushort4 pg[8], pu[8];
  stageB_load_cvt<32>(Bg, 6144, pg, tid);
  stageB_load_cvt<32>(Bu, 6144, pu, tid);

  for (int kt = 0; kt < 768; kt += 64){
    if (kt) __syncthreads();           // previous compute's LDS reads done
    stageB_write<32>(pg, Bgs, tid);
    stageB_write<32>(pu, Bus, tid);
    #pragma unroll
    for (int c = 0; c < 4; c++){
      int r = c * 32 + srow;
      gload16(Ag + (size_t)r * 768 + kt + scol, ldsA + c * 2048);
    }
    __syncthreads();                   // drains vmcnt (A) + lgkm (B writes)
    if (kt + 64 < 768){                // prefetch next B during MFMA phase
      stageB_load_cvt<32>(Bg + (size_t)(kt + 64) * 6144, 6144, pg, tid);
      stageB_load_cvt<32>(Bu + (size_t)(kt + 64) * 6144, 6144, pu, tid);
    }
    #pragma unroll
    for (int kk = 0; kk < 2; kk++){
      short8v af[4], bg[4], bu[4];
      #pragma unroll
      for (int m = 0; m < 4; m++)
        af[m] = *(const short8v*)(As + (wr + m * 16 + fr) * 64 + (((kk * 4 + kg) ^ cA) * 8));
      #pragma unroll
      for (int n = 0; n < 4; n++){
        int kx = kk * 32 + ((kg ^ ((2 * n + f3) & 3)) * 8);
        bg[n] = *(const short8v*)(Bgs + (wc + n * 16 + fr) * BLDP + kx);
        bu[n] = *(const short8v*)(Bus + (wc + n * 16 + fr) * BLDP + kx);
      }
      #pragma unroll
      for (int m = 0; m < 4; m++)
        #pragma unroll
        for (int n = 0; n < 4; n++){
          accg[m][n] = __builtin_amdgcn_mfma_f32_16x16x32_bf16(af[m], bg[n], accg[m][n], 0, 0, 0);
          accu[m][n] = __builtin_amdgcn_mfma_f32_16x16x32_bf16(af[m], bu[n], accu[m][n], 0, 0, 0);
        }
    }
  }
  // epilogue: h_gate/h_up (+bias) -> silu(g)*u -> bf16 act
  #pragma unroll
  for (int n = 0; n < 4; n++){
    int col = n0 + wc + n * 16 + fr;
    float b_g = b1[(size_t)e * 6144 + col];
    float b_u = b1[(size_t)e * 6144 + 3072 + col];
    #pragma unroll
    for (int m = 0; m < 4; m++){
      #pragma unroll
      for (int r = 0; r < 4; r++){
        int row = m0 + wr + m * 16 + kg * 4 + r;
        float hg = accg[m][n][r] + b_g;
        float hu = accu[m][n][r] + b_u;
        float s = (hg / (1.0f + __expf(-hg))) * hu;
        act[((size_t)e * 640 + row) * 3072 + col] = f2bf(s);
      }
    }
  }
}

// ---------------- GEMM2: act @ W2 (fused cvt) + b2 -> y f32 ----------------
__global__ __launch_bounds__(256, 3) void gemm2_kernel(
    const unsigned short* __restrict__ act,
    const float* __restrict__ W2,
    const float* __restrict__ b2,
    float* __restrict__ y)                   // [E][640][768]
{
  __shared__ unsigned short As[128 * 64];
  __shared__ unsigned short Bs[64 * BLDP];
  const int b = blockIdx.x;
  const int w = (b & 7) * 120 + (b >> 3);
  const int mb = w % 5;
  const int nb = (w / 5) % 12;
  const int e  = w / 60;
  const int m0 = mb * 128;
  const int n0 = nb * 64;
  const int tid  = threadIdx.x;
  const int lane = tid & 63;
  const int wv   = tid >> 6;
  const int wr   = (wv & 1) * 64;
  const int wc   = (wv >> 1) * 32;
  const int fr   = lane & 15;
  const int kg   = lane >> 4;
  const int cA   = fr & 7;
  const int f3   = fr >> 3;

  const unsigned short* Ag = act + ((size_t)e * 640 + m0) * 3072;
  const float* Bg = W2 + (size_t)e * 3072 * 768 + n0;

  const int srow = wv * 8 + (lane >> 3);
  const int scol = (((lane & 7) ^ ((lane >> 3) & 7)) * 8);
  unsigned short* ldsA = As + wv * 512;

  f32x4 acc[4][2];
  f32x4 zero4 = {0.f, 0.f, 0.f, 0.f};
  #pragma unroll
  for (int m = 0; m < 4; m++)
    #pragma unroll
    for (int n = 0; n < 2; n++) acc[m][n] = zero4;

  ushort4 pb[4];
  stageB_load_cvt<16>(Bg, 768, pb, tid);

  for (int kt = 0; kt < 3072; kt += 64){
    if (kt) __syncthreads();
    stageB_write<16>(pb, Bs, tid);
    #pragma unroll
    for (int c = 0; c < 4; c++){
      int r = c * 32 + srow;
      gload16(Ag + (size_t)r * 3072 + kt + scol, ldsA + c * 2048);
    }
    __syncthreads();
    if (kt + 64 < 3072)
      stageB_load_cvt<16>(Bg + (size_t)(kt + 64) * 768, 768, pb, tid);
    #pragma unroll
    for (int kk = 0; kk < 2; kk++){
      short8v af[4], bf[2];
      #pragma unroll
      for (int m = 0; m < 4; m++)
        af[m] = *(const short8v*)(As + (wr + m * 16 + fr) * 64 + (((kk * 4 + kg) ^ cA) * 8));
      #pragma unroll
      for (int n = 0; n < 2; n++){
        int kx = kk * 32 + ((kg ^ ((2 * n + f3) & 3)) * 8);
        bf[n] = *(const short8v*)(Bs + (wc + n * 16 + fr) * BLDP + kx);
      }
      #pragma unroll
      for (int m = 0; m < 4; m++)
        #pragma unroll
        for (int n = 0; n < 2; n++)
          acc[m][n] = __builtin_amdgcn_mfma_f32_16x16x32_bf16(af[m], bf[n], acc[m][n], 0, 0, 0);
    }
  }
  float b2v[2];
  #pragma unroll
  for (int n = 0; n < 2; n++) b2v[n] = b2[(size_t)e * 768 + n0 + wc + n * 16 + fr];
  #pragma unroll
  for (int m = 0; m < 4; m++){
    #pragma unroll
    for (int r = 0; r < 4; r++){
      int row = m0 + wr + m * 16 + kg * 4 + r;
      #pragma unroll
      for (int n = 0; n < 2; n++){
        int col = n0 + wc + n * 16 + fr;
        y[((size_t)e * 640 + row) * 768 + col] = acc[m][n][r] + b2v[n];
      }
    }
  }
}

// ---------------- combine-weight scatter: y[e][c] * cw -> out[token] ----------------
__global__ __launch_bounds__(192) void combine_scatter_kernel(
    const float* __restrict__ y, const int* __restrict__ expert_tok,
    const float* __restrict__ cw, float* __restrict__ out)
{
  int ec = blockIdx.x;
  int token = expert_tok[ec];
  if (token < 0) return;
  float w = cw[ec];
  int t4 = threadIdx.x * 4;
  float4 v = *(const float4*)(y + (size_t)ec * 768 + t4);
  v.x *= w; v.y *= w; v.z *= w; v.w *= w;
  *(float4*)(out + (size_t)token * 768 + t4) = v;
}

// ---------------- dense fallback for dropped tokens only ----------------
__global__ __launch_bounds__(256) void fallback_kernel(
    const float* __restrict__ x,
    const float* __restrict__ W1f, const float* __restrict__ b1f,
    const float* __restrict__ W2f, const float* __restrict__ b2f,
    const int* __restrict__ dropped, float* __restrict__ out)
{
  int t = blockIdx.x;
  if (dropped[t] == 0) return;
  __shared__ float xs[768];
  __shared__ float hs[6144];
  int tid = threadIdx.x;
  for (int d = tid; d < 768; d += 256) xs[d] = x[(size_t)t * 768 + d];
  __syncthreads();
  for (int j = tid; j < 6144; j += 256){
    float a = b1f[j];
    for (int d = 0; d < 768; d++) a += xs[d] * W1f[(size_t)d * 6144 + j];
    hs[j] = a;
  }
  __syncthreads();
  for (int j = tid; j < 3072; j += 256){
    float hg = hs[j], hu = hs[j + 3072];
    hs[j] = (hg / (1.0f + __expf(-hg))) * hu;
  }
  __syncthreads();
  for (int d = tid; d < 768; d += 256){
    float a = b2f[d];
    for (int h = 0; h < 3072; h++) a += hs[h] * W2f[(size_t)h * 768 + d];
    out[(size_t)t * 768 + d] = a;   // FALLBACK_W = 1.0
  }
}

extern "C" void kernel_launch(void* const* d_in, const int* in_sizes, int n_in,
                              void* d_out, int out_size, void* d_ws, size_t ws_size,
                              hipStream_t stream) {
  const float* x   = (const float*)d_in[0];
  const float* Wr  = (const float*)d_in[1];
  const float* W1  = (const float*)d_in[2];
  const float* b1  = (const float*)d_in[3];
  const float* W2  = (const float*)d_in[4];
  const float* b2  = (const float*)d_in[5];
  const float* W1f = (const float*)d_in[6];
  const float* b1f = (const float*)d_in[7];
  const float* W2f = (const float*)d_in[8];
  const float* b2f = (const float*)d_in[9];
  float* out = (float*)d_out;

  char* ws = (char*)d_ws;
  int*            expert_tok = (int*)  (ws + 0);          // 16*640*4 = 40960
  float*          cw         = (float*)(ws + 40960);
  int*            eid        = (int*)  (ws + 81920);
  float*          gate       = (float*)(ws + 114688);
  int*            drop       = (int*)  (ws + 147456);
  unsigned short* xa         = (unsigned short*)(ws + 180224);     // 16*640*768*2  = 15728640
  unsigned short* act        = (unsigned short*)(ws + 15908864);   // 16*640*3072*2 = 62914560
  float*          y          = (float*)(ws + 78823424);            // 16*640*768*4  = 31457280
  // total ws use: ~110 MB

  init_tok_kernel<<<40, 256, 0, stream>>>(expert_tok);
  router_kernel<<<2048, 256, 0, stream>>>(x, Wr, eid, gate);
  scan_route_kernel<<<1, 256, 0, stream>>>(eid, gate, expert_tok, cw, drop);
  gather_x_kernel<<<16 * CAP, 192, 0, stream>>>(x, expert_tok, xa);
  gemm1_swiglu_kernel<<<1920, 256, 0, stream>>>(xa, W1, b1, act);
  gemm2_kernel<<<960, 256, 0, stream>>>(act, W2, b2, y);
  combine_scatter_kernel<<<16 * CAP, 192, 0, stream>>>(y, expert_tok, cw, out);
  fallback_kernel<<<NTOK, 256, 0, stream>>>(x, W1f, b1f, W2f, b2f, drop, out);
}